// Round 5
// baseline (262.947 us; speedup 1.0000x reference)
//
#include <hip/hip_runtime.h>
#include <hip/hip_fp16.h>

// Two-hop SpMM-mean. Round 12: attack pass1's write amplification.
//  R11 post-mortem: sort_gather fixed (out of top-5); pass1 now top at
//  67us with WRITE_SIZE=130MB vs 32MB payload (4x amplification) -- the
//  st[pos] scatter writes runs of only ~5.2 edges/bin/chunk (42B) across
//  1563 bins, so every wave store touches ~64 cachelines. R11's bin
//  doubling caused this.
//  Fix (single variable): CHUNK 8192 -> 16384 (EPT 32). Doubles the
//  per-bin run length (84B) and halves chunk count -> halves global
//  bincnt atomic serialization. Bins and sort_gather UNTOUCHED.

#define DIM 64
#define CAP 1536          // per-bin staging capacity (mean 1280, +7.1 sigma)
#define CHUNK 16384       // edges per pass1 workgroup (R12: was 8192)
#define P1B 512
#define EPT (CHUNK / P1B) // 32 edges per thread
#define NBINS 1563        // both hops: 50000/32, 100000/64
#define KREG 6            // ceil(CAP/256) register staging slots

__global__ __launch_bounds__(P1B) void pass1_bin_kernel(
    const int* __restrict__ rows1, const int* __restrict__ cols1,
    const float* __restrict__ vals1, int nnz1, int nc1, int ncb,
    const int* __restrict__ rows2, const int* __restrict__ cols2,
    const float* __restrict__ vals2, int nnz2,
    int* __restrict__ bincnt1, int2* __restrict__ st1,
    int* __restrict__ bincnt2, int2* __restrict__ st2,
    const float4* __restrict__ cvt_in, int2* __restrict__ cvt_out, int n4) {
    __shared__ int hist[NBINS];
    __shared__ int cur[NBINS];
    if ((int)blockIdx.x >= ncb) {
        // fused f32 -> f16 convert (independent stream, overlaps binning)
        int i0 = (blockIdx.x - ncb) * (P1B * 4) + threadIdx.x;
        #pragma unroll
        for (int k = 0; k < 4; ++k) {
            int i = i0 + k * P1B;
            if (i < n4) {
                float4 x = cvt_in[i];
                __half2 h0 = __float22half2_rn(make_float2(x.x, x.y));
                __half2 h1 = __float22half2_rn(make_float2(x.z, x.w));
                int2 pk;
                pk.x = *(int*)&h0;
                pk.y = *(int*)&h1;
                cvt_out[i] = pk;
            }
        }
        return;
    }
    const int* rows; const int* cols; const float* vals;
    int nnz, shift, chunk_id;
    int* bincnt; int2* st;
    if ((int)blockIdx.x < nc1) {
        rows = rows1; cols = cols1; vals = vals1; nnz = nnz1;
        shift = 5; chunk_id = blockIdx.x; bincnt = bincnt1; st = st1;
    } else {
        rows = rows2; cols = cols2; vals = vals2; nnz = nnz2;
        shift = 6; chunk_id = blockIdx.x - nc1; bincnt = bincnt2; st = st2;
    }
    int t = threadIdx.x;
    for (int i = t; i < NBINS; i += P1B) hist[i] = 0;
    __syncthreads();
    int begin = chunk_id * CHUNK;

    int r[EPT]; int c[EPT]; float v[EPT];
    #pragma unroll
    for (int k = 0; k < EPT; ++k) {
        int idx = begin + k * P1B + t;
        bool ok = idx < nnz;
        r[k] = ok ? rows[idx] : -1;
        c[k] = ok ? cols[idx] : 0;
        v[k] = ok ? vals[idx] : 0.0f;
        if (ok) atomicAdd(&hist[r[k] >> shift], 1);
    }
    __syncthreads();
    for (int i = t; i < NBINS; i += P1B) {
        int h = hist[i];
        if (h > 0) cur[i] = i * CAP + atomicAdd(&bincnt[i], h);
    }
    __syncthreads();
    #pragma unroll
    for (int k = 0; k < EPT; ++k) {
        if (r[k] >= 0) {
            int b = r[k] >> shift;
            int pos = atomicAdd(&cur[b], 1);       // LDS atomic
            int key = ((r[k] - (b << shift)) << 17) | c[k];
            st[pos] = make_int2(key, __float_as_int(v[k]));
        }
    }
}

// One WG (256 thr = 4 waves) per bin of RPB rows.  (unchanged from R11)
//  1. stage bin edges into registers + LDS histogram (1 global pass)
//  2. wave-0 in-register shfl prefix scan of row counts
//  3. scatter edges (row-sorted) into LDS from registers
//  4. gather: one wave per row, straight-line 4-deep loads
template <int RPB, bool DST_HALF>
__global__ __launch_bounds__(256, 8) void sort_gather_kernel(
    const int2* __restrict__ st, const int* __restrict__ bincnt,
    const __half* __restrict__ src,
    void* __restrict__ dstv,
    int n_rows) {
    __shared__ int2 edges[CAP];
    __shared__ int excl[RPB];        // row start (within LDS edges[])
    __shared__ int cur[RPB];         // cursor; after scatter = row end
    const int b = blockIdx.x;
    const int t = threadIdx.x;
    const int row0 = b * RPB;
    int cnt_b = min(bincnt[b], CAP);
    const int2* bst = st + (size_t)b * CAP;

    if (t < RPB) cur[t] = 0;
    __syncthreads();
    // stage to registers + histogram (single global read of the bin)
    int2 reg[KREG];
    #pragma unroll
    for (int k = 0; k < KREG; ++k) {
        int i = t + (k << 8);
        bool ok = i < cnt_b;
        reg[k] = ok ? bst[i] : make_int2(-1, 0);
        if (ok) atomicAdd(&cur[reg[k].x >> 17], 1);
    }
    __syncthreads();
    // wave-0 exclusive scan over RPB (<=64) row counts
    if (t < RPB) {
        int c = cur[t];
        int x = c;
        #pragma unroll
        for (int off = 1; off < RPB; off <<= 1) {
            int n = __shfl_up(x, off);
            if (t >= off) x += n;
        }
        excl[t] = x - c;
        cur[t]  = x - c;
    }
    __syncthreads();
    // scatter from registers (row-sorted)
    #pragma unroll
    for (int k = 0; k < KREG; ++k) {
        int key = reg[k].x;
        if (key >= 0) {
            int pos = atomicAdd(&cur[key >> 17], 1);   // LDS atomic
            edges[pos] = make_int2(key & 0x1FFFF, reg[k].y);
        }
    }
    __syncthreads();

    // gather: one wave per row, 4 waves/WG; 16 edges in flight.
    // lane = 16*sub + ld: sub = edge slot, ld = 8B chunk.
    // Straight-line: indices clamped into [start, end-1], tail weights zeroed.
    const int wave = t >> 6;
    const int lane = t & 63;
    const int sub = lane >> 4;
    const int ld  = lane & 15;
    const __half* srcl = src + ld * 4;
    for (int rl = wave; rl < RPB; rl += 4) {
        int row = row0 + rl;
        if (row >= n_rows) break;
        int start = excl[rl];
        int end   = cur[rl];
        float ax = 0.f, ay = 0.f, az = 0.f, aw = 0.f, vsum = 0.f;
        for (int i = start + sub; i < end; i += 16) {
            int lim = end - 1;
            int j1 = min(i + 4,  lim);
            int j2 = min(i + 8,  lim);
            int j3 = min(i + 12, lim);
            int2 e0 = edges[i];
            int2 e1 = edges[j1];
            int2 e2 = edges[j2];
            int2 e3 = edges[j3];
            float v0 = __int_as_float(e0.y);
            float v1 = (i + 4  < end) ? __int_as_float(e1.y) : 0.f;
            float v2 = (i + 8  < end) ? __int_as_float(e2.y) : 0.f;
            float v3 = (i + 12 < end) ? __int_as_float(e3.y) : 0.f;
            int2 r0 = *(const int2*)(srcl + (e0.x << 6));
            int2 r1 = *(const int2*)(srcl + (e1.x << 6));
            int2 r2 = *(const int2*)(srcl + (e2.x << 6));
            int2 r3 = *(const int2*)(srcl + (e3.x << 6));
            float2 a0 = __half22float2(*(__half2*)&r0.x);
            float2 b0 = __half22float2(*(__half2*)&r0.y);
            float2 a1 = __half22float2(*(__half2*)&r1.x);
            float2 b1 = __half22float2(*(__half2*)&r1.y);
            float2 a2 = __half22float2(*(__half2*)&r2.x);
            float2 b2 = __half22float2(*(__half2*)&r2.y);
            float2 a3 = __half22float2(*(__half2*)&r3.x);
            float2 b3 = __half22float2(*(__half2*)&r3.y);
            ax += v0 * a0.x + v1 * a1.x + v2 * a2.x + v3 * a3.x;
            ay += v0 * a0.y + v1 * a1.y + v2 * a2.y + v3 * a3.y;
            az += v0 * b0.x + v1 * b1.x + v2 * b2.x + v3 * b3.x;
            aw += v0 * b0.y + v1 * b1.y + v2 * b2.y + v3 * b3.y;
            vsum += (v0 + v1) + (v2 + v3);
        }
        #pragma unroll
        for (int off = 16; off <= 32; off <<= 1) {
            ax += __shfl_xor(ax, off);
            ay += __shfl_xor(ay, off);
            az += __shfl_xor(az, off);
            aw += __shfl_xor(aw, off);
            vsum += __shfl_xor(vsum, off);
        }
        float d = (vsum == 0.0f) ? 1.0f : vsum;
        if (sub == 0) {
            float inv = 1.0f / d;
            if (DST_HALF) {
                __half* dst = (__half*)dstv;
                __half2 o0 = __float22half2_rn(make_float2(ax * inv, ay * inv));
                __half2 o1 = __float22half2_rn(make_float2(az * inv, aw * inv));
                int2 pk;
                pk.x = *(int*)&o0;
                pk.y = *(int*)&o1;
                *(int2*)(dst + row * DIM + ld * 4) = pk;
            } else {
                float* dst = (float*)dstv;
                float4 o = make_float4(ax * inv, ay * inv, az * inv, aw * inv);
                *(float4*)(dst + row * DIM + ld * 4) = o;
            }
        }
    }
}

extern "C" void kernel_launch(void* const* d_in, const int* in_sizes, int n_in,
                              void* d_out, int out_size, void* d_ws, size_t ws_size,
                              hipStream_t stream) {
    const float* item_emb = (const float*)d_in[1];
    const int*   hv_rows  = (const int*)d_in[2];
    const int*   hv_cols  = (const int*)d_in[3];
    const float* hv_vals  = (const float*)d_in[4];
    const int*   hu_rows  = (const int*)d_in[5];
    const int*   hu_cols  = (const int*)d_in[6];
    const float* hu_vals  = (const float*)d_in[7];

    const int nnz1 = in_sizes[2];
    const int nnz2 = in_sizes[5];
    const int n_items = in_sizes[1] / DIM;   // 100000
    const int n_b  = 50000;
    const int n_u  = out_size / DIM;

    const int nb1 = (n_b + 31) >> 5;         // 1563 bins of 32 rows
    const int nb2 = (n_u + 63) >> 6;         // 1563 bins of 64 rows

    float* out = (float*)d_out;

    // Workspace (~57.6 MB)
    char* p = (char*)d_ws;
    __half* item_h  = (__half*)p; p += (size_t)n_items * DIM * sizeof(__half); // 12.8 MB
    __half* bf_h    = (__half*)p; p += (size_t)n_b * DIM * sizeof(__half);     // 6.4 MB
    int*   bincnt1 = (int*)p;   p += NBINS * sizeof(int);
    int*   bincnt2 = (int*)p;   p += NBINS * sizeof(int);
    int2*  st1     = (int2*)p;  p += (size_t)nb1 * CAP * sizeof(int2);         // 19.2 MB
    int2*  st2     = (int2*)p;  p += (size_t)nb2 * CAP * sizeof(int2);         // 19.2 MB

    hipMemsetAsync(bincnt1, 0, 2 * NBINS * sizeof(int), stream);

    int n4 = n_items * DIM / 4;
    int nc1 = (nnz1 + CHUNK - 1) / CHUNK;
    int nc2 = (nnz2 + CHUNK - 1) / CHUNK;
    int ncb = nc1 + nc2;
    int ncv = (n4 + P1B * 4 - 1) / (P1B * 4);

    pass1_bin_kernel<<<ncb + ncv, P1B, 0, stream>>>(
        hv_rows, hv_cols, hv_vals, nnz1, nc1, ncb,
        hu_rows, hu_cols, hu_vals, nnz2,
        bincnt1, st1, bincnt2, st2,
        (const float4*)item_emb, (int2*)item_h, n4);

    // Hop 1: item_h -> bf_h   (50000 rows, 32 rows/bin)
    sort_gather_kernel<32, true><<<nb1, 256, 0, stream>>>(
        st1, bincnt1, item_h, bf_h, n_b);
    // Hop 2: bf_h -> out      (100000 rows, 64 rows/bin)
    sort_gather_kernel<64, false><<<nb2, 256, 0, stream>>>(
        st2, bincnt2, bf_h, out, n_u);
}

// Round 8
// 252.257 us; speedup vs baseline: 1.0424x; 1.0424x over previous
//
#include <hip/hip_runtime.h>
#include <hip/hip_fp16.h>

// Two-hop SpMM-mean. Round 15: RECOVERY — proven pieces, serial dispatches.
//  R13 (coop launch) silently no-opped; R14 (manual grid barrier) hung the
//  container twice: grid-wide sync in this harness is a dead end. Revert to
//  plain dispatches and compose best-measured components:
//   - pass1 with fused f32->f16, 782 bins/hop (R10 measured config; pass1
//     write-amp blows up at 1563 bins, so stay at 782)
//   - sort_gather at R9's measured-best geometry (512 thr, 64/128 rows/bin,
//     CAP 2944) but with the R11 register-staged single-global-read sort
//     (4 barriers instead of 14, kills the 2nd bst read: -19MB FETCH/hop)
//   - gather loop: R9 straight-line 4-deep (best measured; 3 structures
//     tried, all within noise -> don't touch it)

#define DIM 64
#define CAP 2944          // per-bin staging (mean 2558, +7.6 sigma)
#define CHUNK 8192
#define P1B 512
#define EPT (CHUNK / P1B) // 16
#define NBIN 782          // ceil(50000/64) == ceil(100000/128)
#define SH1 6             // hop1: 64 rows/bin
#define SH2 7             // hop2: 128 rows/bin
#define KR 6              // ceil(CAP/512) register staging slots

__global__ __launch_bounds__(P1B) void pass1_bin_kernel(
    const int* __restrict__ rows1, const int* __restrict__ cols1,
    const float* __restrict__ vals1, int nnz1, int nc1, int ncb,
    const int* __restrict__ rows2, const int* __restrict__ cols2,
    const float* __restrict__ vals2, int nnz2,
    int* __restrict__ bincnt1, int2* __restrict__ st1,
    int* __restrict__ bincnt2, int2* __restrict__ st2,
    const float4* __restrict__ cvt_in, int2* __restrict__ cvt_out, int n4) {
    __shared__ int hist[NBIN];
    __shared__ int cur[NBIN];
    if ((int)blockIdx.x >= ncb) {
        // fused f32 -> f16 convert (independent stream, overlaps binning)
        int i0 = (blockIdx.x - ncb) * (P1B * 4) + threadIdx.x;
        #pragma unroll
        for (int k = 0; k < 4; ++k) {
            int i = i0 + k * P1B;
            if (i < n4) {
                float4 x = cvt_in[i];
                __half2 h0 = __float22half2_rn(make_float2(x.x, x.y));
                __half2 h1 = __float22half2_rn(make_float2(x.z, x.w));
                int2 pk;
                pk.x = *(int*)&h0;
                pk.y = *(int*)&h1;
                cvt_out[i] = pk;
            }
        }
        return;
    }
    const int* rows; const int* cols; const float* vals;
    int nnz, shift, chunk_id;
    int* bincnt; int2* st;
    if ((int)blockIdx.x < nc1) {
        rows = rows1; cols = cols1; vals = vals1; nnz = nnz1;
        shift = SH1; chunk_id = blockIdx.x; bincnt = bincnt1; st = st1;
    } else {
        rows = rows2; cols = cols2; vals = vals2; nnz = nnz2;
        shift = SH2; chunk_id = blockIdx.x - nc1; bincnt = bincnt2; st = st2;
    }
    int t = threadIdx.x;
    for (int i = t; i < NBIN; i += P1B) hist[i] = 0;
    __syncthreads();
    int begin = chunk_id * CHUNK;

    int r[EPT]; int c[EPT]; float v[EPT];
    #pragma unroll
    for (int k = 0; k < EPT; ++k) {
        int idx = begin + k * P1B + t;
        bool ok = idx < nnz;
        r[k] = ok ? rows[idx] : -1;
        c[k] = ok ? cols[idx] : 0;
        v[k] = ok ? vals[idx] : 0.0f;
        if (ok) atomicAdd(&hist[r[k] >> shift], 1);
    }
    __syncthreads();
    for (int i = t; i < NBIN; i += P1B) {
        int h = hist[i];
        if (h > 0) cur[i] = i * CAP + atomicAdd(&bincnt[i], h);
    }
    __syncthreads();
    #pragma unroll
    for (int k = 0; k < EPT; ++k) {
        if (r[k] >= 0) {
            int b = r[k] >> shift;
            int pos = atomicAdd(&cur[b], 1);       // LDS atomic
            int key = ((r[k] - (b << shift)) << 17) | c[k];
            st[pos] = make_int2(key, __float_as_int(v[k]));
        }
    }
}

// One WG (512 thr = 8 waves) per bin of RPB rows.
//  1. stage bin edges into registers + LDS histogram (ONE global read)
//  2. shfl exclusive scan of row counts (1 or 2 waves via wsum relay)
//  3. scatter edges row-sorted into LDS from registers
//  4. gather: one wave per row, straight-line 4-deep loads (R9 form)
template <int RPB, bool DST_HALF>
__global__ __launch_bounds__(512, 8) void sort_gather_kernel(
    const int2* __restrict__ st, const int* __restrict__ bincnt,
    const __half* __restrict__ src,
    void* __restrict__ dstv,
    int n_rows) {
    __shared__ int2 edges[CAP];
    __shared__ int excl[RPB];        // row start (within LDS edges[])
    __shared__ int cur[RPB];         // cursor; after scatter = row end
    __shared__ int wsum[2];
    const int b = blockIdx.x;
    const int t = threadIdx.x;
    const int row0 = b * RPB;
    int cnt_b = min(bincnt[b], CAP);
    const int2* bst = st + (size_t)b * CAP;

    if (t < RPB) cur[t] = 0;
    __syncthreads();
    // stage bin edges to registers + LDS histogram (one global read)
    int2 reg[KR];
    #pragma unroll
    for (int k = 0; k < KR; ++k) {
        int i = t + k * P1B;
        bool ok = i < cnt_b;
        reg[k] = ok ? bst[i] : make_int2(-1, 0);
        if (ok) atomicAdd(&cur[reg[k].x >> 17], 1);
    }
    __syncthreads();
    // exclusive scan over RPB row counts (wave 0, plus wave relay if RPB=128)
    if (t < RPB) {
        int cc = cur[t];
        int x = cc;
        #pragma unroll
        for (int off = 1; off < 64; off <<= 1) {
            int n = __shfl_up(x, off);
            if ((t & 63) >= off) x += n;
        }
        excl[t] = x - cc;                        // wave-local exclusive
        if (RPB > 64 && (t & 63) == 63) wsum[t >> 6] = x;
    }
    __syncthreads();
    if (t < RPB) {
        int e = excl[t];
        if (RPB > 64 && t >= 64) e += wsum[0];
        excl[t] = e;
        cur[t]  = e;
    }
    __syncthreads();
    // scatter from registers (row-sorted into LDS)
    #pragma unroll
    for (int k = 0; k < KR; ++k) {
        int key = reg[k].x;
        if (key >= 0) {
            int pos = atomicAdd(&cur[key >> 17], 1);  // LDS atomic
            edges[pos] = make_int2(key & 0x1FFFF, reg[k].y);
        }
    }
    __syncthreads();

    // gather: one wave per row, 8 waves; 16 edges in flight.
    // lane = 16*sub + ld: sub = edge slot, ld = 8B chunk.
    // Straight-line: indices clamped into [start, end-1], tail weights zeroed.
    const int wave = t >> 6;
    const int lane = t & 63;
    const int sub = lane >> 4;
    const int ld  = lane & 15;
    const __half* srcl = src + ld * 4;
    for (int rl = wave; rl < RPB; rl += 8) {
        int row = row0 + rl;
        if (row >= n_rows) break;
        int start = excl[rl];
        int end   = cur[rl];
        float ax = 0.f, ay = 0.f, az = 0.f, aw = 0.f, vsum = 0.f;
        for (int i = start + sub; i < end; i += 16) {
            int lim = end - 1;
            int j1 = min(i + 4,  lim);
            int j2 = min(i + 8,  lim);
            int j3 = min(i + 12, lim);
            int2 e0 = edges[i];
            int2 e1 = edges[j1];
            int2 e2 = edges[j2];
            int2 e3 = edges[j3];
            float v0 = __int_as_float(e0.y);
            float v1 = (i + 4  < end) ? __int_as_float(e1.y) : 0.f;
            float v2 = (i + 8  < end) ? __int_as_float(e2.y) : 0.f;
            float v3 = (i + 12 < end) ? __int_as_float(e3.y) : 0.f;
            int2 r0 = *(const int2*)(srcl + (e0.x << 6));
            int2 r1 = *(const int2*)(srcl + (e1.x << 6));
            int2 r2 = *(const int2*)(srcl + (e2.x << 6));
            int2 r3 = *(const int2*)(srcl + (e3.x << 6));
            float2 a0 = __half22float2(*(__half2*)&r0.x);
            float2 b0 = __half22float2(*(__half2*)&r0.y);
            float2 a1 = __half22float2(*(__half2*)&r1.x);
            float2 b1 = __half22float2(*(__half2*)&r1.y);
            float2 a2 = __half22float2(*(__half2*)&r2.x);
            float2 b2 = __half22float2(*(__half2*)&r2.y);
            float2 a3 = __half22float2(*(__half2*)&r3.x);
            float2 b3 = __half22float2(*(__half2*)&r3.y);
            ax += v0 * a0.x + v1 * a1.x + v2 * a2.x + v3 * a3.x;
            ay += v0 * a0.y + v1 * a1.y + v2 * a2.y + v3 * a3.y;
            az += v0 * b0.x + v1 * b1.x + v2 * b2.x + v3 * b3.x;
            aw += v0 * b0.y + v1 * b1.y + v2 * b2.y + v3 * b3.y;
            vsum += (v0 + v1) + (v2 + v3);
        }
        #pragma unroll
        for (int off = 16; off <= 32; off <<= 1) {
            ax += __shfl_xor(ax, off);
            ay += __shfl_xor(ay, off);
            az += __shfl_xor(az, off);
            aw += __shfl_xor(aw, off);
            vsum += __shfl_xor(vsum, off);
        }
        float d = (vsum == 0.0f) ? 1.0f : vsum;
        if (sub == 0) {
            float inv = 1.0f / d;
            if (DST_HALF) {
                __half* dst = (__half*)dstv;
                __half2 o0 = __float22half2_rn(make_float2(ax * inv, ay * inv));
                __half2 o1 = __float22half2_rn(make_float2(az * inv, aw * inv));
                int2 pk;
                pk.x = *(int*)&o0;
                pk.y = *(int*)&o1;
                *(int2*)(dst + row * DIM + ld * 4) = pk;
            } else {
                float* dst = (float*)dstv;
                float4 o = make_float4(ax * inv, ay * inv, az * inv, aw * inv);
                *(float4*)(dst + row * DIM + ld * 4) = o;
            }
        }
    }
}

extern "C" void kernel_launch(void* const* d_in, const int* in_sizes, int n_in,
                              void* d_out, int out_size, void* d_ws, size_t ws_size,
                              hipStream_t stream) {
    const float* item_emb = (const float*)d_in[1];
    const int*   hv_rows  = (const int*)d_in[2];
    const int*   hv_cols  = (const int*)d_in[3];
    const float* hv_vals  = (const float*)d_in[4];
    const int*   hu_rows  = (const int*)d_in[5];
    const int*   hu_cols  = (const int*)d_in[6];
    const float* hu_vals  = (const float*)d_in[7];

    const int nnz1 = in_sizes[2];
    const int nnz2 = in_sizes[5];
    const int n_items = in_sizes[1] / DIM;   // 100000
    const int n_b  = 50000;
    const int n_u  = out_size / DIM;

    float* out = (float*)d_out;

    // Workspace (~56 MB)
    char* p = (char*)d_ws;
    __half* item_h  = (__half*)p; p += (size_t)n_items * DIM * sizeof(__half); // 12.8 MB
    __half* bf_h    = (__half*)p; p += (size_t)n_b * DIM * sizeof(__half);     // 6.4 MB
    int*   bincnt1 = (int*)p;   p += NBIN * sizeof(int);
    int*   bincnt2 = (int*)p;   p += NBIN * sizeof(int);
    int2*  st1     = (int2*)p;  p += (size_t)NBIN * CAP * sizeof(int2);        // 18.4 MB
    int2*  st2     = (int2*)p;  p += (size_t)NBIN * CAP * sizeof(int2);        // 18.4 MB

    hipMemsetAsync(bincnt1, 0, 2 * NBIN * sizeof(int), stream);

    int n4 = n_items * DIM / 4;
    int nc1 = (nnz1 + CHUNK - 1) / CHUNK;
    int nc2 = (nnz2 + CHUNK - 1) / CHUNK;
    int ncb = nc1 + nc2;
    int ncv = (n4 + P1B * 4 - 1) / (P1B * 4);

    pass1_bin_kernel<<<ncb + ncv, P1B, 0, stream>>>(
        hv_rows, hv_cols, hv_vals, nnz1, nc1, ncb,
        hu_rows, hu_cols, hu_vals, nnz2,
        bincnt1, st1, bincnt2, st2,
        (const float4*)item_emb, (int2*)item_h, n4);

    // Hop 1: item_h -> bf_h   (50000 rows, 64 rows/bin)
    sort_gather_kernel<64, true><<<NBIN, 512, 0, stream>>>(
        st1, bincnt1, item_h, bf_h, n_b);
    // Hop 2: bf_h -> out      (100000 rows, 128 rows/bin)
    sort_gather_kernel<128, false><<<NBIN, 512, 0, stream>>>(
        st2, bincnt2, bf_h, out, n_u);
}